// Round 9
// baseline (216.980 us; speedup 1.0000x reference)
//
#include <hip/hip_runtime.h>

#define B_ 8
#define C_ 256
#define C8_ 32
#define N_ 4096

typedef __bf16 bf16;
typedef __bf16 bf16x4 __attribute__((ext_vector_type(4)));
typedef __bf16 bf16x8 __attribute__((ext_vector_type(8)));
typedef float f32x4 __attribute__((ext_vector_type(4)));
typedef float f32x16 __attribute__((ext_vector_type(16)));

#if __has_builtin(__builtin_amdgcn_exp2f)
#define EXP2 __builtin_amdgcn_exp2f
#else
#define EXP2 exp2f
#endif

#define CVTPK(lo, hi) ({ unsigned int _w;                                     \
  asm("v_cvt_pk_bf16_f32 %0, %1, %2" : "=v"(_w) : "v"(lo), "v"(hi)); _w; })
#define LSWAP(a, b) asm("v_permlane32_swap_b32 %0, %1" : "+v"(a), "+v"(b))

// async global->LDS, 16B per lane; dest = uniform base + lane*16
#define GLD16(gp, lp) __builtin_amdgcn_global_load_lds(                       \
    (const __attribute__((address_space(1))) void*)(gp),                      \
    (__attribute__((address_space(3))) void*)(lp), 16, 0, 0)
#define VMW(n) do { asm volatile("s_waitcnt vmcnt(" n ")" ::: "memory");      \
    __builtin_amdgcn_sched_barrier(0); } while (0)

// ---------------- weights f32 -> bf16 (once) --------------------------------
__global__ __launch_bounds__(256) void k_convw(const float* __restrict__ wq,
    const float* __restrict__ wk, const float* __restrict__ wv,
    bf16* __restrict__ Wb) {
  int i = (blockIdx.x * 256 + threadIdx.x) * 4;
  const float* src; int off;
  if (i < 8192) { src = wq; off = i; }
  else if (i < 16384) { src = wk; off = i - 8192; }
  else { src = wv; off = i - 16384; }
  f32x4 v = *reinterpret_cast<const f32x4*>(src + off);
  bf16x4 o;
  o[0] = (bf16)v[0]; o[1] = (bf16)v[1]; o[2] = (bf16)v[2]; o[3] = (bf16)v[3];
  *reinterpret_cast<bf16x4*>(Wb + i) = o;
}

// ---------------- transpose + convert: x[b][c][n] f32 -> xT[b][n][c] bf16 ----
__global__ __launch_bounds__(256) void k_transpose(const float* __restrict__ x,
                                                   bf16* __restrict__ xT) {
  __shared__ bf16 t[64][72];
  int bid = blockIdx.x;
  int b = bid & 7, rem = bid >> 3;
  int c0 = (rem >> 6) * 64, n0 = (rem & 63) * 64;
  int tid = threadIdx.x;
#pragma unroll
  for (int r = 0; r < 4; ++r) {
    int cc = r * 16 + (tid >> 4);
    int j = (tid & 15) * 4;
    f32x4 v = *reinterpret_cast<const f32x4*>(
        x + ((size_t)b * C_ + c0 + cc) * N_ + n0 + j);
    bf16x4 o;
    o[0] = (bf16)v[0]; o[1] = (bf16)v[1]; o[2] = (bf16)v[2]; o[3] = (bf16)v[3];
    *reinterpret_cast<bf16x4*>(&t[cc][j]) = o;
  }
  __syncthreads();
#pragma unroll
  for (int r = 0; r < 2; ++r) {
    int nn = r * 32 + (tid >> 3);
    int c8 = (tid & 7) * 8;
    bf16x8 o;
#pragma unroll
    for (int k = 0; k < 8; ++k) o[k] = t[c8 + k][nn];
    *reinterpret_cast<bf16x8*>(
        xT + ((size_t)b * N_ + n0 + nn) * C_ + c0 + c8) = o;
  }
}

// ------------- Q/K projection. Q: [b][n][32] scaled by log2e.  --------------
// K: FRAGMENT-MAJOR Kt[b][mt][f][64][8]
__global__ __launch_bounds__(256) void k_proj_qk(const bf16* __restrict__ xT,
    const bf16* __restrict__ Wb,
    const float* __restrict__ bq, const float* __restrict__ bk,
    bf16* __restrict__ Qt, bf16* __restrict__ Kt) {
  int bid = blockIdx.x;
  int b = bid & 7, nt = bid >> 3;
  const bf16* W = Wb + (blockIdx.y ? 8192 : 0);
  const float* bias = blockIdx.y ? bk : bq;
  int tid = threadIdx.x, lane = tid & 63, w = tid >> 6;
  int ln = lane & 31, h = lane >> 5;
  int n0 = nt * 128 + w * 32;
  const bf16* xp = xT + ((size_t)b * N_ + n0 + ln) * C_ + h * 8;
  const bf16* wp = W + (size_t)ln * C_ + h * 8;
  f32x16 acc;
#pragma unroll
  for (int r = 0; r < 16; ++r) acc[r] = 0.f;
#pragma unroll
  for (int ck = 0; ck < C_; ck += 16) {
    bf16x8 af = *reinterpret_cast<const bf16x8*>(xp + ck);
    bf16x8 bfg = *reinterpret_cast<const bf16x8*>(wp + ck);
    acc = __builtin_amdgcn_mfma_f32_32x32x16_bf16(af, bfg, acc, 0, 0, 0);
  }
  float bb = bias[ln];
  if (blockIdx.y) {   // K -> fragment-major
    int f = (ln >> 4) & 1, hA = (ln >> 3) & 1, e = ln & 7;
#pragma unroll
    for (int r = 0; r < 16; ++r) {
      int n = n0 + (r & 3) + 8 * (r >> 2) + 4 * h;
      int mt = n >> 5, lm = n & 31;
      Kt[((size_t)(b * 128 + mt) * 2 + f) * 512 + (lm + hA * 32) * 8 + e] =
          (bf16)(acc[r] + bb);
    }
  } else {            // Q -> n-major, log2e folded
#pragma unroll
    for (int r = 0; r < 16; ++r) {
      int n = n0 + (r & 3) + 8 * (r >> 2) + 4 * h;
      Qt[((size_t)b * N_ + n) * C8_ + ln] = (bf16)((acc[r] + bb) * 1.44269504f);
    }
  }
}

// ------------- V projection -> FRAGMENT-MAJOR Vt[b][mt][f=ct*2+j][64][8] ----
__global__ __launch_bounds__(256) void k_proj_v(const bf16* __restrict__ xT,
    const bf16* __restrict__ Wb, const float* __restrict__ bv,
    bf16* __restrict__ Vt) {
  int bid = blockIdx.x;
  int b = bid & 7, rem = bid >> 3;
  int ot = rem >> 5, nt = rem & 31;
  int tid = threadIdx.x, lane = tid & 63, w = tid >> 6;
  int ln = lane & 31, h = lane >> 5;
  int o0 = ot * 32;
  int n0 = nt * 128 + w * 32;
  const bf16* wp = Wb + 16384 + (size_t)(o0 + ln) * C_ + h * 8;
  const bf16* xp = xT + ((size_t)b * N_ + n0 + ln) * C_ + h * 8;
  f32x16 acc;
#pragma unroll
  for (int r = 0; r < 16; ++r) acc[r] = 0.f;
#pragma unroll
  for (int ck = 0; ck < C_; ck += 16) {
    bf16x8 afg = *reinterpret_cast<const bf16x8*>(wp + ck);
    bf16x8 bfg = *reinterpret_cast<const bf16x8*>(xp + ck);
    acc = __builtin_amdgcn_mfma_f32_32x32x16_bf16(afg, bfg, acc, 0, 0, 0);
  }
  int mt = n0 >> 5;
  bf16* tb = Vt + (size_t)(b * 128 + mt) * 8192;
  int ct = o0 >> 5;
  int j = (ln >> 4) & 1, hA = (ln >> 3) & 1, e = ln & 7;
#pragma unroll
  for (int r = 0; r < 16; ++r) {
    int cc = (r & 3) + 8 * (r >> 2) + 4 * h;     // c - o0
    tb[(ct * 2 + j) * 512 + (cc + hA * 32) * 8 + e] = (bf16)(acc[r] + bv[o0 + cc]);
  }
}

// ---------------- flash attention: 64q x 128ch x m-half waves ---------------
// 512 blocks x 4 waves = (ch, mh). Wave: 64 iters over 32-m tiles, 2 q-tiles.
// Per iter: issue K(t+1)+V(t+1)->buf[nxt], ONE vmcnt(8) (leaves this iter's
// V DMA in flight) -> QK x2 (K frag shared) -> dual softmax -> PV 16 MFMA from
// buf[cur] (no wait needed: its DMA drained at the vmcnt). Never drain to 0.
__global__ __launch_bounds__(256, 2) void k_attn(const bf16* __restrict__ Qt,
    const bf16* __restrict__ Kt, const bf16* __restrict__ Vt,
    const float* __restrict__ x, float* __restrict__ out) {
  __shared__ __align__(16) char sbuf[66560];  // V dbuf (64KB) ∪ Ob[2][128][65] f32
  __shared__ float sML[2][2][2][32];          // [mh][qi][{M,L}][q]
  int bid = blockIdx.x;
  int b = bid & 7;                            // batch == XCD
  int qt = bid >> 3;                          // 0..63
  int n0 = qt * 64;
  int tid = threadIdx.x, lane = tid & 63, w = tid >> 6;
  int ln = lane & 31, h = lane >> 5;
  int ch = w >> 1, mh = w & 1;
  char* buf0 = sbuf + w * 16384;
  char* buf1 = buf0 + 8192;

  const bf16* qp = Qt + ((size_t)b * N_ + n0 + ln) * C8_ + h * 8;
  bf16x8 qf00 = *reinterpret_cast<const bf16x8*>(qp);
  bf16x8 qf01 = *reinterpret_cast<const bf16x8*>(qp + 16);
  bf16x8 qf10 = *reinterpret_cast<const bf16x8*>(qp + 1024);
  bf16x8 qf11 = *reinterpret_cast<const bf16x8*>(qp + 1024 + 16);
  const bf16* Kb = Kt + (size_t)(b * 128 + mh * 64) * 1024 + (size_t)lane * 8;
  const char* Vg = (const char*)(Vt + (size_t)(b * 128 + mh * 64) * 8192
                                 + ch * 4096) + (size_t)lane * 16;

  f32x16 o[8];                               // [qi*4 + ct]
#pragma unroll
  for (int ct = 0; ct < 8; ++ct)
#pragma unroll
    for (int r = 0; r < 16; ++r) o[ct][r] = 0.f;
  float M0v = -1e30f, L0v = 0.f, M1v = -1e30f, L1v = 0.f;

  // prologue: K(0) to regs, V(0) -> buf0
  bf16x8 kf0 = *reinterpret_cast<const bf16x8*>(Kb);
  bf16x8 kf1 = *reinterpret_cast<const bf16x8*>(Kb + 512);
#pragma unroll
  for (int f = 0; f < 8; ++f) GLD16(Vg + f * 1024, buf0 + f * 1024);

  char* bc = buf0;
  char* bn = buf1;
#pragma unroll 1
  for (int it = 0; it < 64; ++it) {
    int itn = it + 1 > 63 ? 63 : it + 1;
    // K(t+1) first (older than the V DMAs -> drained by the vmcnt(8))
    bf16x8 kn0 = *reinterpret_cast<const bf16x8*>(Kb + (size_t)itn * 1024);
    bf16x8 kn1 = *reinterpret_cast<const bf16x8*>(Kb + (size_t)itn * 1024 + 512);
    // V(t+1) -> buf[nxt]
    const char* vg = Vg + (size_t)itn * 16384;
#pragma unroll
    for (int f = 0; f < 8; ++f) GLD16(vg + f * 1024, bn + f * 1024);

    // single wait: everything except this iter's 8 V-DMAs is complete
    VMW("8");

    // ---- QK for both q-tiles (K frags shared)
    f32x16 s0, s1;
#pragma unroll
    for (int r = 0; r < 16; ++r) { s0[r] = 0.f; s1[r] = 0.f; }
    s0 = __builtin_amdgcn_mfma_f32_32x32x16_bf16(kf0, qf00, s0, 0, 0, 0);
    s0 = __builtin_amdgcn_mfma_f32_32x32x16_bf16(kf1, qf01, s0, 0, 0, 0);
    s1 = __builtin_amdgcn_mfma_f32_32x32x16_bf16(kf0, qf10, s1, 0, 0, 0);
    s1 = __builtin_amdgcn_mfma_f32_32x32x16_bf16(kf1, qf11, s1, 0, 0, 0);

    // ---- dual softmax (independent chains)
    float wm0 = fmaxf(fmaxf(fmaxf(s0[0], s0[1]), fmaxf(s0[2], s0[3])),
                      fmaxf(fmaxf(s0[4], s0[5]), fmaxf(s0[6], s0[7])));
    wm0 = fmaxf(wm0, fmaxf(fmaxf(fmaxf(s0[8], s0[9]), fmaxf(s0[10], s0[11])),
                           fmaxf(fmaxf(s0[12], s0[13]), fmaxf(s0[14], s0[15]))));
    float wm1 = fmaxf(fmaxf(fmaxf(s1[0], s1[1]), fmaxf(s1[2], s1[3])),
                      fmaxf(fmaxf(s1[4], s1[5]), fmaxf(s1[6], s1[7])));
    wm1 = fmaxf(wm1, fmaxf(fmaxf(fmaxf(s1[8], s1[9]), fmaxf(s1[10], s1[11])),
                           fmaxf(fmaxf(s1[12], s1[13]), fmaxf(s1[14], s1[15]))));
    wm0 = fmaxf(wm0, __shfl_xor(wm0, 32));
    wm1 = fmaxf(wm1, __shfl_xor(wm1, 32));
    if (__any(wm0 > M0v + 8.f)) {            // defer-max (T13)
      float Mn = fmaxf(M0v, wm0);
      float sc = EXP2(M0v - Mn);
      L0v *= sc;
#pragma unroll
      for (int ct = 0; ct < 4; ++ct)
#pragma unroll
        for (int r = 0; r < 16; ++r) o[ct][r] *= sc;
      M0v = Mn;
    }
    if (__any(wm1 > M1v + 8.f)) {
      float Mn = fmaxf(M1v, wm1);
      float sc = EXP2(M1v - Mn);
      L1v *= sc;
#pragma unroll
      for (int ct = 4; ct < 8; ++ct)
#pragma unroll
        for (int r = 0; r < 16; ++r) o[ct][r] *= sc;
      M1v = Mn;
    }
#pragma unroll
    for (int r = 0; r < 16; ++r) { s0[r] = EXP2(s0[r] - M0v); s1[r] = EXP2(s1[r] - M1v); }
    {
      float a0 = (s0[0] + s0[1]) + (s0[2] + s0[3]);
      float a1 = (s0[4] + s0[5]) + (s0[6] + s0[7]);
      float a2 = (s0[8] + s0[9]) + (s0[10] + s0[11]);
      float a3 = (s0[12] + s0[13]) + (s0[14] + s0[15]);
      L0v += (a0 + a1) + (a2 + a3);
      float b0 = (s1[0] + s1[1]) + (s1[2] + s1[3]);
      float b1 = (s1[4] + s1[5]) + (s1[6] + s1[7]);
      float b2 = (s1[8] + s1[9]) + (s1[10] + s1[11]);
      float b3 = (s1[12] + s1[13]) + (s1[14] + s1[15]);
      L1v += (b0 + b1) + (b2 + b3);
    }

    // P -> bf16 frags in-register (T12), both tiles
    union Pu { unsigned int u[4]; bf16x8 v; } P00, P01, P10, P11;
    {
      unsigned int c0 = CVTPK(s0[0], s0[1]),   c1 = CVTPK(s0[2], s0[3]);
      unsigned int c2 = CVTPK(s0[4], s0[5]),   c3 = CVTPK(s0[6], s0[7]);
      unsigned int c4 = CVTPK(s0[8], s0[9]),   c5 = CVTPK(s0[10], s0[11]);
      unsigned int c6 = CVTPK(s0[12], s0[13]), c7 = CVTPK(s0[14], s0[15]);
      LSWAP(c0, c2); LSWAP(c1, c3); LSWAP(c4, c6); LSWAP(c5, c7);
      P00.u[0] = c0; P00.u[1] = c1; P00.u[2] = c2; P00.u[3] = c3;
      P01.u[0] = c4; P01.u[1] = c5; P01.u[2] = c6; P01.u[3] = c7;
    }
    {
      unsigned int c0 = CVTPK(s1[0], s1[1]),   c1 = CVTPK(s1[2], s1[3]);
      unsigned int c2 = CVTPK(s1[4], s1[5]),   c3 = CVTPK(s1[6], s1[7]);
      unsigned int c4 = CVTPK(s1[8], s1[9]),   c5 = CVTPK(s1[10], s1[11]);
      unsigned int c6 = CVTPK(s1[12], s1[13]), c7 = CVTPK(s1[14], s1[15]);
      LSWAP(c0, c2); LSWAP(c1, c3); LSWAP(c4, c6); LSWAP(c5, c7);
      P10.u[0] = c0; P10.u[1] = c1; P10.u[2] = c2; P10.u[3] = c3;
      P11.u[0] = c4; P11.u[1] = c5; P11.u[2] = c6; P11.u[3] = c7;
    }

    // ---- PV from buf[cur]: each V frag pair feeds both q-tiles
    __builtin_amdgcn_s_setprio(1);
#pragma unroll
    for (int ct = 0; ct < 4; ++ct) {
      bf16x8 vf0 = *reinterpret_cast<const bf16x8*>(bc + (2 * ct) * 1024 + lane * 16);
      bf16x8 vf1 = *reinterpret_cast<const bf16x8*>(bc + (2 * ct + 1) * 1024 + lane * 16);
      o[ct]     = __builtin_amdgcn_mfma_f32_32x32x16_bf16(vf0, P00.v, o[ct], 0, 0, 0);
      o[4 + ct] = __builtin_amdgcn_mfma_f32_32x32x16_bf16(vf0, P10.v, o[4 + ct], 0, 0, 0);
      o[ct]     = __builtin_amdgcn_mfma_f32_32x32x16_bf16(vf1, P01.v, o[ct], 0, 0, 0);
      o[4 + ct] = __builtin_amdgcn_mfma_f32_32x32x16_bf16(vf1, P11.v, o[4 + ct], 0, 0, 0);
    }
    __builtin_amdgcn_s_setprio(0);

    kf0 = kn0; kf1 = kn1;
    char* tmp = bc; bc = bn; bn = tmp;
  }
  VMW("0");                                  // drain before Ob aliases V bufs

  // ---- publish M/L, merge the two m-halves ----
  L0v += __shfl_xor(L0v, 32);
  L1v += __shfl_xor(L1v, 32);
  if (ch == 0 && lane < 32) {
    sML[mh][0][0][lane] = M0v; sML[mh][0][1][lane] = L0v;
    sML[mh][1][0][lane] = M1v; sML[mh][1][1][lane] = L1v;
  }
  __syncthreads();
  float (*Ob)[128][65] = reinterpret_cast<float (*)[128][65]>(sbuf);
  float iv[2], am[2];
#pragma unroll
  for (int qi = 0; qi < 2; ++qi) {
    float Ma = sML[0][qi][0][ln], La = sML[0][qi][1][ln];
    float Mb = sML[1][qi][0][ln], Lb = sML[1][qi][1][ln];
    float Ms = fmaxf(Ma, Mb);
    float a0 = EXP2(Ma - Ms), a1 = EXP2(Mb - Ms);
    iv[qi] = 1.f / (La * a0 + Lb * a1);
    am[qi] = mh ? a1 : a0;
  }
  if (mh) {
#pragma unroll
    for (int qi = 0; qi < 2; ++qi)
#pragma unroll
      for (int ct = 0; ct < 4; ++ct)
#pragma unroll
        for (int r = 0; r < 16; ++r) {
          int cl = ct * 32 + (r & 3) + 8 * (r >> 2) + 4 * h;
          Ob[ch][cl][qi * 32 + ln] = o[qi * 4 + ct][r] * am[qi];
        }
  }
  __syncthreads();
  if (!mh) {
#pragma unroll
    for (int qi = 0; qi < 2; ++qi)
#pragma unroll
      for (int ct = 0; ct < 4; ++ct)
#pragma unroll
        for (int r = 0; r < 16; ++r) {
          int cl = ct * 32 + (r & 3) + 8 * (r >> 2) + 4 * h;
          size_t idx = ((size_t)b * C_ + ch * 128 + cl) * N_ + n0 + qi * 32 + ln;
          out[idx] = (o[qi * 4 + ct][r] * am[qi] + Ob[ch][cl][qi * 32 + ln]) * iv[qi]
                     + x[idx];
        }
  }
}

extern "C" void kernel_launch(void* const* d_in, const int* in_sizes, int n_in,
                              void* d_out, int out_size, void* d_ws, size_t ws_size,
                              hipStream_t stream) {
  const float* x  = (const float*)d_in[0];
  const float* wq = (const float*)d_in[1];
  const float* bq = (const float*)d_in[2];
  const float* wk = (const float*)d_in[3];
  const float* bk = (const float*)d_in[4];
  const float* wv = (const float*)d_in[5];
  const float* bv = (const float*)d_in[6];
  float* out = (float*)d_out;

  bf16* xT = (bf16*)d_ws;
  bf16* Qt = xT + (size_t)B_ * N_ * C_;
  bf16* Kt = Qt + (size_t)B_ * N_ * C8_;
  bf16* Vt = Kt + (size_t)B_ * N_ * C8_;
  bf16* Wb = Vt + (size_t)B_ * N_ * C_;

  k_convw<<<dim3(80), dim3(256), 0, stream>>>(wq, wk, wv, Wb);
  k_transpose<<<dim3(2048), dim3(256), 0, stream>>>(x, xT);
  k_proj_qk<<<dim3(256, 2), dim3(256), 0, stream>>>(xT, Wb, bq, bk, Qt, Kt);
  k_proj_v<<<dim3(2048), dim3(256), 0, stream>>>(xT, Wb, bv, Vt);
  k_attn<<<dim3(512), dim3(256), 0, stream>>>(Qt, Kt, Vt, x, out);
}

// Round 11
// 184.912 us; speedup vs baseline: 1.1734x; 1.1734x over previous
//
#include <hip/hip_runtime.h>

#define B_ 8
#define C_ 256
#define C8_ 32
#define N_ 4096

typedef __bf16 bf16;
typedef __bf16 bf16x4 __attribute__((ext_vector_type(4)));
typedef __bf16 bf16x8 __attribute__((ext_vector_type(8)));
typedef float f32x4 __attribute__((ext_vector_type(4)));
typedef float f32x16 __attribute__((ext_vector_type(16)));

#if __has_builtin(__builtin_amdgcn_exp2f)
#define EXP2 __builtin_amdgcn_exp2f
#else
#define EXP2 exp2f
#endif

#define CVTPK(lo, hi) ({ unsigned int _w;                                     \
  asm("v_cvt_pk_bf16_f32 %0, %1, %2" : "=v"(_w) : "v"(lo), "v"(hi)); _w; })
// NOTE: operands MUST be distinct values (distinct registers). Copy-then-swap
// reductions coalesce to one register and silently break (R10 lesson).
#define LSWAP(a, b) asm("v_permlane32_swap_b32 %0, %1" : "+v"(a), "+v"(b))

// async global->LDS, 16B per lane; dest = uniform base + lane*16
#define GLD16(gp, lp) __builtin_amdgcn_global_load_lds(                       \
    (const __attribute__((address_space(1))) void*)(gp),                      \
    (__attribute__((address_space(3))) void*)(lp), 16, 0, 0)
#define VMW(n) do { asm volatile("s_waitcnt vmcnt(" n ")" ::: "memory");      \
    __builtin_amdgcn_sched_barrier(0); } while (0)
#define SBAR() __builtin_amdgcn_sched_barrier(0)

// ---------------- weights f32 -> bf16 (once) --------------------------------
__global__ __launch_bounds__(256) void k_convw(const float* __restrict__ wq,
    const float* __restrict__ wk, const float* __restrict__ wv,
    bf16* __restrict__ Wb) {
  int i = (blockIdx.x * 256 + threadIdx.x) * 4;
  const float* src; int off;
  if (i < 8192) { src = wq; off = i; }
  else if (i < 16384) { src = wk; off = i - 8192; }
  else { src = wv; off = i - 16384; }
  f32x4 v = *reinterpret_cast<const f32x4*>(src + off);
  bf16x4 o;
  o[0] = (bf16)v[0]; o[1] = (bf16)v[1]; o[2] = (bf16)v[2]; o[3] = (bf16)v[3];
  *reinterpret_cast<bf16x4*>(Wb + i) = o;
}

// ---------------- transpose + convert: x[b][c][n] f32 -> xT[b][n][c] bf16 ----
__global__ __launch_bounds__(256) void k_transpose(const float* __restrict__ x,
                                                   bf16* __restrict__ xT) {
  __shared__ bf16 t[64][72];
  int bid = blockIdx.x;
  int b = bid & 7, rem = bid >> 3;
  int c0 = (rem >> 6) * 64, n0 = (rem & 63) * 64;
  int tid = threadIdx.x;
#pragma unroll
  for (int r = 0; r < 4; ++r) {
    int cc = r * 16 + (tid >> 4);
    int j = (tid & 15) * 4;
    f32x4 v = *reinterpret_cast<const f32x4*>(
        x + ((size_t)b * C_ + c0 + cc) * N_ + n0 + j);
    bf16x4 o;
    o[0] = (bf16)v[0]; o[1] = (bf16)v[1]; o[2] = (bf16)v[2]; o[3] = (bf16)v[3];
    *reinterpret_cast<bf16x4*>(&t[cc][j]) = o;
  }
  __syncthreads();
#pragma unroll
  for (int r = 0; r < 2; ++r) {
    int nn = r * 32 + (tid >> 3);
    int c8 = (tid & 7) * 8;
    bf16x8 o;
#pragma unroll
    for (int k = 0; k < 8; ++k) o[k] = t[c8 + k][nn];
    *reinterpret_cast<bf16x8*>(
        xT + ((size_t)b * N_ + n0 + nn) * C_ + c0 + c8) = o;
  }
}

// ------------- Q/K projection. Q: [b][n][32] scaled by log2e.  --------------
// K: FRAGMENT-MAJOR Kt[b][mt][f][64][8]
__global__ __launch_bounds__(256) void k_proj_qk(const bf16* __restrict__ xT,
    const bf16* __restrict__ Wb,
    const float* __restrict__ bq, const float* __restrict__ bk,
    bf16* __restrict__ Qt, bf16* __restrict__ Kt) {
  int bid = blockIdx.x;
  int b = bid & 7, nt = bid >> 3;
  const bf16* W = Wb + (blockIdx.y ? 8192 : 0);
  const float* bias = blockIdx.y ? bk : bq;
  int tid = threadIdx.x, lane = tid & 63, w = tid >> 6;
  int ln = lane & 31, h = lane >> 5;
  int n0 = nt * 128 + w * 32;
  const bf16* xp = xT + ((size_t)b * N_ + n0 + ln) * C_ + h * 8;
  const bf16* wp = W + (size_t)ln * C_ + h * 8;
  f32x16 acc;
#pragma unroll
  for (int r = 0; r < 16; ++r) acc[r] = 0.f;
#pragma unroll
  for (int ck = 0; ck < C_; ck += 16) {
    bf16x8 af = *reinterpret_cast<const bf16x8*>(xp + ck);
    bf16x8 bfg = *reinterpret_cast<const bf16x8*>(wp + ck);
    acc = __builtin_amdgcn_mfma_f32_32x32x16_bf16(af, bfg, acc, 0, 0, 0);
  }
  float bb = bias[ln];
  if (blockIdx.y) {   // K -> fragment-major
    int f = (ln >> 4) & 1, hA = (ln >> 3) & 1, e = ln & 7;
#pragma unroll
    for (int r = 0; r < 16; ++r) {
      int n = n0 + (r & 3) + 8 * (r >> 2) + 4 * h;
      int mt = n >> 5, lm = n & 31;
      Kt[((size_t)(b * 128 + mt) * 2 + f) * 512 + (lm + hA * 32) * 8 + e] =
          (bf16)(acc[r] + bb);
    }
  } else {            // Q -> n-major, log2e folded
#pragma unroll
    for (int r = 0; r < 16; ++r) {
      int n = n0 + (r & 3) + 8 * (r >> 2) + 4 * h;
      Qt[((size_t)b * N_ + n) * C8_ + ln] = (bf16)((acc[r] + bb) * 1.44269504f);
    }
  }
}

// ------------- V projection -> FRAGMENT-MAJOR Vt[b][mt][f=ct*2+j][64][8] ----
__global__ __launch_bounds__(256) void k_proj_v(const bf16* __restrict__ xT,
    const bf16* __restrict__ Wb, const float* __restrict__ bv,
    bf16* __restrict__ Vt) {
  int bid = blockIdx.x;
  int b = bid & 7, rem = bid >> 3;
  int ot = rem >> 5, nt = rem & 31;
  int tid = threadIdx.x, lane = tid & 63, w = tid >> 6;
  int ln = lane & 31, h = lane >> 5;
  int o0 = ot * 32;
  int n0 = nt * 128 + w * 32;
  const bf16* wp = Wb + 16384 + (size_t)(o0 + ln) * C_ + h * 8;
  const bf16* xp = xT + ((size_t)b * N_ + n0 + ln) * C_ + h * 8;
  f32x16 acc;
#pragma unroll
  for (int r = 0; r < 16; ++r) acc[r] = 0.f;
#pragma unroll
  for (int ck = 0; ck < C_; ck += 16) {
    bf16x8 afg = *reinterpret_cast<const bf16x8*>(wp + ck);
    bf16x8 bfg = *reinterpret_cast<const bf16x8*>(xp + ck);
    acc = __builtin_amdgcn_mfma_f32_32x32x16_bf16(afg, bfg, acc, 0, 0, 0);
  }
  int mt = n0 >> 5;
  bf16* tb = Vt + (size_t)(b * 128 + mt) * 8192;
  int ct = o0 >> 5;
  int j = (ln >> 4) & 1, hA = (ln >> 3) & 1, e = ln & 7;
#pragma unroll
  for (int r = 0; r < 16; ++r) {
    int cc = (r & 3) + 8 * (r >> 2) + 4 * h;     // c - o0
    tb[(ct * 2 + j) * 512 + (cc + hA * 32) * 8 + e] = (bf16)(acc[r] + bv[o0 + cc]);
  }
}

// ---------------- flash attention: R7 structure + 1-iter DMA lead -----------
// 1024 blocks x 4 waves, barrier-free, 2 waves/SIMD. Wave w owns m-quarter
// (32 tiles), all 256 channels, o[8]=128 acc. Ping-pong half-buffers with
// counted vmcnt: VMW(10) drains A(t) [issued LAST iter], PV-h0, reissue A(t+1);
// VMW(8) drains B(t)+K(t+1), PV-h1, reissue B(t+1). Never drain to 0 in-loop.
__global__ __launch_bounds__(256, 2) void k_attn(const bf16* __restrict__ Qt,
    const bf16* __restrict__ Kt, const bf16* __restrict__ Vt,
    const float* __restrict__ x, float* __restrict__ out) {
  __shared__ __align__(16) char sbuf[67584];   // V bufs (64KB) ∪ merge Ob (66KB)
  __shared__ float sML[4][2][32];
  int bid = blockIdx.x;
  int b = bid & 7;                     // batch == XCD
  int qt = bid >> 3;
  int n0 = qt * 32;
  int tid = threadIdx.x, lane = tid & 63, w = tid >> 6;
  int ln = lane & 31, h = lane >> 5;
  char* bufA = sbuf + w * 16384;
  char* bufB = bufA + 8192;

  const bf16* qp = Qt + ((size_t)b * N_ + n0 + ln) * C8_ + h * 8;
  bf16x8 qf0 = *reinterpret_cast<const bf16x8*>(qp);
  bf16x8 qf1 = *reinterpret_cast<const bf16x8*>(qp + 16);
  const bf16* Kb = Kt + (size_t)(b * 128 + w * 32) * 1024 + (size_t)lane * 8;
  const char* Vg = (const char*)(Vt + (size_t)(b * 128 + w * 32) * 8192)
                   + (size_t)lane * 16;

  f32x16 o[8];
#pragma unroll
  for (int ct = 0; ct < 8; ++ct)
#pragma unroll
    for (int r = 0; r < 16; ++r) o[ct][r] = 0.f;
  float M = -1e30f, L = 0.f;

  // ---- prologue: K(0) regs, V(0) DMA (A then B), drain K only ----
  bf16x8 kf0 = *reinterpret_cast<const bf16x8*>(Kb);
  bf16x8 kf1 = *reinterpret_cast<const bf16x8*>(Kb + 512);
#pragma unroll
  for (int f = 0; f < 8; ++f) GLD16(Vg + f * 1024, bufA + f * 1024);
#pragma unroll
  for (int f = 0; f < 8; ++f) GLD16(Vg + 8192 + f * 1024, bufB + f * 1024);
  VMW("16");                           // K(0) drained; 16 V-DMAs in flight

#pragma unroll 1
  for (int it = 0; it < 32; ++it) {
    int itn = it + 1 > 31 ? 31 : it + 1;
    // K(t+1) -> regs (drained at this iter's VMW(8))
    bf16x8 kn0 = *reinterpret_cast<const bf16x8*>(Kb + (size_t)itn * 1024);
    bf16x8 kn1 = *reinterpret_cast<const bf16x8*>(Kb + (size_t)itn * 1024 + 512);
    const char* vg = Vg + (size_t)itn * 16384;

    // ---- S = K x Q
    f32x16 s;
#pragma unroll
    for (int r = 0; r < 16; ++r) s[r] = 0.f;
    s = __builtin_amdgcn_mfma_f32_32x32x16_bf16(kf0, qf0, s, 0, 0, 0);
    s = __builtin_amdgcn_mfma_f32_32x32x16_bf16(kf1, qf1, s, 0, 0, 0);

    // ---- softmax
    float m0 = fmaxf(fmaxf(fmaxf(s[0], s[1]), fmaxf(s[2], s[3])),
                     fmaxf(fmaxf(s[4], s[5]), fmaxf(s[6], s[7])));
    float m1 = fmaxf(fmaxf(fmaxf(s[8], s[9]), fmaxf(s[10], s[11])),
                     fmaxf(fmaxf(s[12], s[13]), fmaxf(s[14], s[15])));
    float wm = fmaxf(m0, m1);
    wm = fmaxf(wm, __shfl_xor(wm, 32));   // R7-proven reduction
    bool resc = __any(wm > M + 8.f);      // defer-max (T13)
    if (resc) {
      float Mn = fmaxf(M, wm);
      float sc = EXP2(M - Mn);
      L *= sc;
#pragma unroll
      for (int ct = 0; ct < 8; ++ct)
#pragma unroll
        for (int r = 0; r < 16; ++r) o[ct][r] *= sc;
      M = Mn;
    }
#pragma unroll
    for (int r = 0; r < 16; ++r) s[r] = EXP2(s[r] - M);
    float q0 = (s[0] + s[1]) + (s[2] + s[3]);
    float q1 = (s[4] + s[5]) + (s[6] + s[7]);
    float q2 = (s[8] + s[9]) + (s[10] + s[11]);
    float q3 = (s[12] + s[13]) + (s[14] + s[15]);
    L += (q0 + q1) + (q2 + q3);

    // P -> bf16 frags in-register (T12; operands all distinct values)
    unsigned int c0 = CVTPK(s[0], s[1]),   c1 = CVTPK(s[2], s[3]);
    unsigned int c2 = CVTPK(s[4], s[5]),   c3 = CVTPK(s[6], s[7]);
    unsigned int c4 = CVTPK(s[8], s[9]),   c5 = CVTPK(s[10], s[11]);
    unsigned int c6 = CVTPK(s[12], s[13]), c7 = CVTPK(s[14], s[15]);
    LSWAP(c0, c2); LSWAP(c1, c3); LSWAP(c4, c6); LSWAP(c5, c7);
    union { unsigned int u[4]; bf16x8 v; } P0, P1;
    P0.u[0] = c0; P0.u[1] = c1; P0.u[2] = c2; P0.u[3] = c3;
    P1.u[0] = c4; P1.u[1] = c5; P1.u[2] = c6; P1.u[3] = c7;

    // ---- PV h0 from bufA: A(t) was issued one iteration ago
    VMW("10");                           // drains A(t); leaves B(t)+K(t+1)
    __builtin_amdgcn_s_setprio(1);
#pragma unroll
    for (int ct = 0; ct < 4; ++ct) {
      bf16x8 vf0 = *reinterpret_cast<const bf16x8*>(bufA + (2 * ct) * 1024 + lane * 16);
      bf16x8 vf1 = *reinterpret_cast<const bf16x8*>(bufA + (2 * ct + 1) * 1024 + lane * 16);
      o[ct] = __builtin_amdgcn_mfma_f32_32x32x16_bf16(vf0, P0.v, o[ct], 0, 0, 0);
      o[ct] = __builtin_amdgcn_mfma_f32_32x32x16_bf16(vf1, P1.v, o[ct], 0, 0, 0);
    }
    __builtin_amdgcn_s_setprio(0);
    SBAR();                              // keep GLD below the ds_reads above
#pragma unroll
    for (int f = 0; f < 8; ++f) GLD16(vg + f * 1024, bufA + f * 1024);

    // ---- PV h1 from bufB
    VMW("8");                            // drains B(t) + K(t+1)
    __builtin_amdgcn_s_setprio(1);
#pragma unroll
    for (int ct = 4; ct < 8; ++ct) {
      bf16x8 vf0 = *reinterpret_cast<const bf16x8*>(bufB + (2 * (ct - 4)) * 1024 + lane * 16);
      bf16x8 vf1 = *reinterpret_cast<const bf16x8*>(bufB + (2 * (ct - 4) + 1) * 1024 + lane * 16);
      o[ct] = __builtin_amdgcn_mfma_f32_32x32x16_bf16(vf0, P0.v, o[ct], 0, 0, 0);
      o[ct] = __builtin_amdgcn_mfma_f32_32x32x16_bf16(vf1, P1.v, o[ct], 0, 0, 0);
    }
    __builtin_amdgcn_s_setprio(0);
    SBAR();
#pragma unroll
    for (int f = 0; f < 8; ++f) GLD16(vg + 8192 + f * 1024, bufB + f * 1024);

    kf0 = kn0; kf1 = kn1;
  }
  VMW("0");                              // drain before Ob aliases V bufs

  // ---- 4-way merge (V bufs dead; Ob aliases them) ----
  float (*Ob)[256][33] = reinterpret_cast<float (*)[256][33]>(sbuf);
  L += __shfl_xor(L, 32);                // R7-proven reduction
  if (lane < 32) { sML[w][0][lane] = M; sML[w][1][lane] = L; }
  __syncthreads();
  float Ms = fmaxf(fmaxf(sML[0][0][ln], sML[1][0][ln]),
                   fmaxf(sML[2][0][ln], sML[3][0][ln]));
  float Lt = sML[0][1][ln] * EXP2(sML[0][0][ln] - Ms)
           + sML[1][1][ln] * EXP2(sML[1][0][ln] - Ms)
           + sML[2][1][ln] * EXP2(sML[2][0][ln] - Ms)
           + sML[3][1][ln] * EXP2(sML[3][0][ln] - Ms);
  float inv = 1.f / Lt;
  float a = EXP2(M - Ms);
  int half = w >> 1;                 // waves {0,1}->buf0, {2,3}->buf1
  if (!(w & 1)) {
#pragma unroll
    for (int ct = 0; ct < 8; ++ct)
#pragma unroll
      for (int r = 0; r < 16; ++r) {
        int c = ct * 32 + (r & 3) + 8 * (r >> 2) + 4 * h;
        Ob[half][c][ln] = o[ct][r] * a;
      }
  }
  __syncthreads();
  if (w & 1) {
#pragma unroll
    for (int ct = 0; ct < 8; ++ct)
#pragma unroll
      for (int r = 0; r < 16; ++r) {
        int c = ct * 32 + (r & 3) + 8 * (r >> 2) + 4 * h;
        Ob[half][c][ln] += o[ct][r] * a;
      }
  }
  __syncthreads();
#pragma unroll
  for (int ct2 = 0; ct2 < 2; ++ct2)
#pragma unroll
    for (int r = 0; r < 16; ++r) {
      int c = w * 64 + ct2 * 32 + (r & 3) + 8 * (r >> 2) + 4 * h;
      size_t idx = ((size_t)b * C_ + c) * N_ + n0 + ln;
      out[idx] = (Ob[0][c][ln] + Ob[1][c][ln]) * inv + x[idx];
    }
}

extern "C" void kernel_launch(void* const* d_in, const int* in_sizes, int n_in,
                              void* d_out, int out_size, void* d_ws, size_t ws_size,
                              hipStream_t stream) {
  const float* x  = (const float*)d_in[0];
  const float* wq = (const float*)d_in[1];
  const float* bq = (const float*)d_in[2];
  const float* wk = (const float*)d_in[3];
  const float* bk = (const float*)d_in[4];
  const float* wv = (const float*)d_in[5];
  const float* bv = (const float*)d_in[6];
  float* out = (float*)d_out;

  bf16* xT = (bf16*)d_ws;
  bf16* Qt = xT + (size_t)B_ * N_ * C_;
  bf16* Kt = Qt + (size_t)B_ * N_ * C8_;
  bf16* Vt = Kt + (size_t)B_ * N_ * C8_;
  bf16* Wb = Vt + (size_t)B_ * N_ * C_;

  k_convw<<<dim3(80), dim3(256), 0, stream>>>(wq, wk, wv, Wb);
  k_transpose<<<dim3(2048), dim3(256), 0, stream>>>(x, xT);
  k_proj_qk<<<dim3(256, 2), dim3(256), 0, stream>>>(xT, Wb, bq, bk, Qt, Kt);
  k_proj_v<<<dim3(2048), dim3(256), 0, stream>>>(xT, Wb, bv, Vt);
  k_attn<<<dim3(1024), dim3(256), 0, stream>>>(Qt, Kt, Vt, x, out);
}

// Round 12
// 151.337 us; speedup vs baseline: 1.4338x; 1.2219x over previous
//
#include <hip/hip_runtime.h>

#define B_ 8
#define C_ 256
#define C8_ 32
#define N_ 4096

typedef __bf16 bf16;
typedef __bf16 bf16x4 __attribute__((ext_vector_type(4)));
typedef __bf16 bf16x8 __attribute__((ext_vector_type(8)));
typedef float f32x4 __attribute__((ext_vector_type(4)));
typedef float f32x16 __attribute__((ext_vector_type(16)));

#if __has_builtin(__builtin_amdgcn_exp2f)
#define EXP2 __builtin_amdgcn_exp2f
#else
#define EXP2 exp2f
#endif

#define CVTPK(lo, hi) ({ unsigned int _w;                                     \
  asm("v_cvt_pk_bf16_f32 %0, %1, %2" : "=v"(_w) : "v"(lo), "v"(hi)); _w; })
// NOTE: operands MUST be distinct values (R10 lesson: copy-then-swap breaks).
#define LSWAP(a, b) asm("v_permlane32_swap_b32 %0, %1" : "+v"(a), "+v"(b))

#define GLD16(gp, lp) __builtin_amdgcn_global_load_lds(                       \
    (const __attribute__((address_space(1))) void*)(gp),                      \
    (__attribute__((address_space(3))) void*)(lp), 16, 0, 0)
#define VMW(n) do { asm volatile("s_waitcnt vmcnt(" n ")" ::: "memory");      \
    __builtin_amdgcn_sched_barrier(0); } while (0)
#define RBAR() __builtin_amdgcn_s_barrier()   // raw: does NOT drain vmcnt

// ---------------- weights f32 -> bf16 (once) --------------------------------
__global__ __launch_bounds__(256) void k_convw(const float* __restrict__ wq,
    const float* __restrict__ wk, const float* __restrict__ wv,
    bf16* __restrict__ Wb) {
  int i = (blockIdx.x * 256 + threadIdx.x) * 4;
  const float* src; int off;
  if (i < 8192) { src = wq; off = i; }
  else if (i < 16384) { src = wk; off = i - 8192; }
  else { src = wv; off = i - 16384; }
  f32x4 v = *reinterpret_cast<const f32x4*>(src + off);
  bf16x4 o;
  o[0] = (bf16)v[0]; o[1] = (bf16)v[1]; o[2] = (bf16)v[2]; o[3] = (bf16)v[3];
  *reinterpret_cast<bf16x4*>(Wb + i) = o;
}

// ---------------- transpose + convert: x[b][c][n] f32 -> xT[b][n][c] bf16 ----
__global__ __launch_bounds__(256) void k_transpose(const float* __restrict__ x,
                                                   bf16* __restrict__ xT) {
  __shared__ bf16 t[64][72];
  int bid = blockIdx.x;
  int b = bid & 7, rem = bid >> 3;
  int c0 = (rem >> 6) * 64, n0 = (rem & 63) * 64;
  int tid = threadIdx.x;
#pragma unroll
  for (int r = 0; r < 4; ++r) {
    int cc = r * 16 + (tid >> 4);
    int j = (tid & 15) * 4;
    f32x4 v = *reinterpret_cast<const f32x4*>(
        x + ((size_t)b * C_ + c0 + cc) * N_ + n0 + j);
    bf16x4 o;
    o[0] = (bf16)v[0]; o[1] = (bf16)v[1]; o[2] = (bf16)v[2]; o[3] = (bf16)v[3];
    *reinterpret_cast<bf16x4*>(&t[cc][j]) = o;
  }
  __syncthreads();
#pragma unroll
  for (int r = 0; r < 2; ++r) {
    int nn = r * 32 + (tid >> 3);
    int c8 = (tid & 7) * 8;
    bf16x8 o;
#pragma unroll
    for (int k = 0; k < 8; ++k) o[k] = t[c8 + k][nn];
    *reinterpret_cast<bf16x8*>(
        xT + ((size_t)b * N_ + n0 + nn) * C_ + c0 + c8) = o;
  }
}

// ------------- fused Q/K/V projection: xT strip read ONCE -------------------
// grid 256 = (8 b x 32 nt). Wave = 32 n. xf[16] in regs; Q,K, then 8 V o-tiles
// stream W from L2. Outputs identical layouts to R11 (Q n-major log2e,
// K frag-major, Vt frag-major).
__global__ __launch_bounds__(256) void k_proj_all(const bf16* __restrict__ xT,
    const bf16* __restrict__ Wb, const float* __restrict__ bq,
    const float* __restrict__ bk, const float* __restrict__ bv,
    bf16* __restrict__ Qt, bf16* __restrict__ Kt, bf16* __restrict__ Vt) {
  int bid = blockIdx.x;
  int b = bid & 7, nt = bid >> 3;
  int tid = threadIdx.x, lane = tid & 63, w = tid >> 6;
  int ln = lane & 31, h = lane >> 5;
  int n0 = nt * 128 + w * 32;
  const bf16* xp = xT + ((size_t)b * N_ + n0 + ln) * C_ + h * 8;

  bf16x8 xf[16];
#pragma unroll
  for (int k = 0; k < 16; ++k) xf[k] = *reinterpret_cast<const bf16x8*>(xp + k * 16);

  // ---- Q (o-tile 0): acc = x * W^T ; write n-major, log2e folded
  {
    const bf16* wp = Wb + (size_t)ln * C_ + h * 8;
    bf16x8 wf[16];
#pragma unroll
    for (int k = 0; k < 16; ++k) wf[k] = *reinterpret_cast<const bf16x8*>(wp + k * 16);
    f32x16 acc;
#pragma unroll
    for (int r = 0; r < 16; ++r) acc[r] = 0.f;
#pragma unroll
    for (int k = 0; k < 16; ++k)
      acc = __builtin_amdgcn_mfma_f32_32x32x16_bf16(xf[k], wf[k], acc, 0, 0, 0);
    float bb = bq[ln];
#pragma unroll
    for (int r = 0; r < 16; ++r) {
      int n = n0 + (r & 3) + 8 * (r >> 2) + 4 * h;
      Qt[((size_t)b * N_ + n) * C8_ + ln] = (bf16)((acc[r] + bb) * 1.44269504f);
    }
  }
  // ---- K (o-tile 1): write fragment-major
  {
    const bf16* wp = Wb + 8192 + (size_t)ln * C_ + h * 8;
    bf16x8 wf[16];
#pragma unroll
    for (int k = 0; k < 16; ++k) wf[k] = *reinterpret_cast<const bf16x8*>(wp + k * 16);
    f32x16 acc;
#pragma unroll
    for (int r = 0; r < 16; ++r) acc[r] = 0.f;
#pragma unroll
    for (int k = 0; k < 16; ++k)
      acc = __builtin_amdgcn_mfma_f32_32x32x16_bf16(xf[k], wf[k], acc, 0, 0, 0);
    float bb = bk[ln];
    int f = (ln >> 4) & 1, hA = (ln >> 3) & 1, e = ln & 7;
#pragma unroll
    for (int r = 0; r < 16; ++r) {
      int n = n0 + (r & 3) + 8 * (r >> 2) + 4 * h;
      int mt = n >> 5, lm = n & 31;
      Kt[((size_t)(b * 128 + mt) * 2 + f) * 512 + (lm + hA * 32) * 8 + e] =
          (bf16)(acc[r] + bb);
    }
  }
  // ---- V (8 o-tiles): acc = W * x ; write fragment-major Vt
  int mt = n0 >> 5;
  bf16* tb = Vt + (size_t)(b * 128 + mt) * 8192;
  int j = (ln >> 4) & 1, hA = (ln >> 3) & 1, e = ln & 7;
#pragma unroll 1
  for (int ot = 0; ot < 8; ++ot) {
    const bf16* wp = Wb + 16384 + (size_t)(ot * 32 + ln) * C_ + h * 8;
    bf16x8 wf[16];
#pragma unroll
    for (int k = 0; k < 16; ++k) wf[k] = *reinterpret_cast<const bf16x8*>(wp + k * 16);
    f32x16 acc;
#pragma unroll
    for (int r = 0; r < 16; ++r) acc[r] = 0.f;
#pragma unroll
    for (int k = 0; k < 16; ++k)
      acc = __builtin_amdgcn_mfma_f32_32x32x16_bf16(wf[k], xf[k], acc, 0, 0, 0);
#pragma unroll
    for (int r = 0; r < 16; ++r) {
      int cc = (r & 3) + 8 * (r >> 2) + 4 * h;
      tb[(ot * 2 + j) * 512 + (cc + hA * 32) * 8 + e] =
          (bf16)(acc[r] + bv[ot * 32 + cc]);
    }
  }
}

// ---------------- flash attention: 64q blocks, V shared across q-pair -------
// 512 blocks x 4 waves = (qh = w&1, mh = w>>1). Wave: 32q, 256c, m-half
// (64 tiles). Per iter: both qh waves of an mh group DMA half of tile(t+1)
// into the shared double buffer; VMW(8) drains own tile-t half + K(t+1);
// raw s_barrier confirms partner; PV reads whole 16KB buffer; barrier after
// PV frees it. V L2-traffic halved vs R11. Counted vmcnt, never 0 in-loop.
__global__ __launch_bounds__(256, 2) void k_attn(const bf16* __restrict__ Qt,
    const bf16* __restrict__ Kt, const bf16* __restrict__ Vt,
    const float* __restrict__ x, float* __restrict__ out) {
  __shared__ __align__(16) char sbuf[67584];   // V bufs 4x16KB ∪ Ob[2][256][33]
  __shared__ float sML[2][2][2][32];           // [mh][qh][{M,L}][q]
  int bid = blockIdx.x;
  int b = bid & 7;                     // batch == XCD
  int qt = bid >> 3;                   // 0..63
  int tid = threadIdx.x, lane = tid & 63, w = tid >> 6;
  int ln = lane & 31, h = lane >> 5;
  int qh = w & 1, mh = w >> 1;
  int n0 = qt * 64 + qh * 32;
  char* bufs = sbuf + mh * 32768;      // this mh-group's two 16KB buffers

  const bf16* qp = Qt + ((size_t)b * N_ + n0 + ln) * C8_ + h * 8;
  bf16x8 qf0 = *reinterpret_cast<const bf16x8*>(qp);
  bf16x8 qf1 = *reinterpret_cast<const bf16x8*>(qp + 16);
  const bf16* Kb = Kt + (size_t)(b * 128 + mh * 64) * 1024 + (size_t)lane * 8;
  const char* Vg = (const char*)(Vt + (size_t)(b * 128 + mh * 64) * 8192)
                   + (size_t)lane * 16;

  f32x16 o[8];
#pragma unroll
  for (int ct = 0; ct < 8; ++ct)
#pragma unroll
    for (int r = 0; r < 16; ++r) o[ct][r] = 0.f;
  float M = -1e30f, L = 0.f;

  // ---- prologue: K(0) regs, own half of tile0 -> buf[0], drain K only ----
  bf16x8 kf0 = *reinterpret_cast<const bf16x8*>(Kb);
  bf16x8 kf1 = *reinterpret_cast<const bf16x8*>(Kb + 512);
#pragma unroll
  for (int f = 0; f < 8; ++f)
    GLD16(Vg + (qh * 8 + f) * 1024, bufs + (qh * 8 + f) * 1024);
  VMW("8");                            // K(0) drained; 8 tile0-DMAs in flight

  int pp = 0;
#pragma unroll 1
  for (int it = 0; it < 64; ++it) {
    int itn = it + 1 > 63 ? 63 : it + 1;
    // K(t+1) -> regs (drained at this iter's VMW(8))
    bf16x8 kn0 = *reinterpret_cast<const bf16x8*>(Kb + (size_t)itn * 1024);
    bf16x8 kn1 = *reinterpret_cast<const bf16x8*>(Kb + (size_t)itn * 1024 + 512);
    // own half of tile(t+1) -> buf[pp^1]
    const char* vg = Vg + (size_t)itn * 16384;
    char* bn = bufs + (pp ^ 1) * 16384;
#pragma unroll
    for (int f = 0; f < 8; ++f)
      GLD16(vg + (qh * 8 + f) * 1024, bn + (qh * 8 + f) * 1024);

    // ---- S = K x Q
    f32x16 s;
#pragma unroll
    for (int r = 0; r < 16; ++r) s[r] = 0.f;
    s = __builtin_amdgcn_mfma_f32_32x32x16_bf16(kf0, qf0, s, 0, 0, 0);
    s = __builtin_amdgcn_mfma_f32_32x32x16_bf16(kf1, qf1, s, 0, 0, 0);

    // ---- softmax
    float m0 = fmaxf(fmaxf(fmaxf(s[0], s[1]), fmaxf(s[2], s[3])),
                     fmaxf(fmaxf(s[4], s[5]), fmaxf(s[6], s[7])));
    float m1 = fmaxf(fmaxf(fmaxf(s[8], s[9]), fmaxf(s[10], s[11])),
                     fmaxf(fmaxf(s[12], s[13]), fmaxf(s[14], s[15])));
    float wm = fmaxf(m0, m1);
    wm = fmaxf(wm, __shfl_xor(wm, 32));
    bool resc = __any(wm > M + 8.f);     // defer-max (T13)
    if (resc) {
      float Mn = fmaxf(M, wm);
      float sc = EXP2(M - Mn);
      L *= sc;
#pragma unroll
      for (int ct = 0; ct < 8; ++ct)
#pragma unroll
        for (int r = 0; r < 16; ++r) o[ct][r] *= sc;
      M = Mn;
    }
#pragma unroll
    for (int r = 0; r < 16; ++r) s[r] = EXP2(s[r] - M);
    float q0 = (s[0] + s[1]) + (s[2] + s[3]);
    float q1 = (s[4] + s[5]) + (s[6] + s[7]);
    float q2 = (s[8] + s[9]) + (s[10] + s[11]);
    float q3 = (s[12] + s[13]) + (s[14] + s[15]);
    L += (q0 + q1) + (q2 + q3);

    // P -> bf16 frags in-register (T12)
    unsigned int c0 = CVTPK(s[0], s[1]),   c1 = CVTPK(s[2], s[3]);
    unsigned int c2 = CVTPK(s[4], s[5]),   c3 = CVTPK(s[6], s[7]);
    unsigned int c4 = CVTPK(s[8], s[9]),   c5 = CVTPK(s[10], s[11]);
    unsigned int c6 = CVTPK(s[12], s[13]), c7 = CVTPK(s[14], s[15]);
    LSWAP(c0, c2); LSWAP(c1, c3); LSWAP(c4, c6); LSWAP(c5, c7);
    union { unsigned int u[4]; bf16x8 v; } P0, P1;
    P0.u[0] = c0; P0.u[1] = c1; P0.u[2] = c2; P0.u[3] = c3;
    P1.u[0] = c4; P1.u[1] = c5; P1.u[2] = c6; P1.u[3] = c7;

    // own tile-t half + K(t+1) complete; partner's half confirmed by barrier
    VMW("8");
    RBAR();

    // ---- PV: whole shared 16KB buffer (both halves)
    char* bc = bufs + pp * 16384;
    __builtin_amdgcn_s_setprio(1);
#pragma unroll
    for (int ct = 0; ct < 8; ++ct) {
      bf16x8 vf0 = *reinterpret_cast<const bf16x8*>(bc + (2 * ct) * 1024 + lane * 16);
      bf16x8 vf1 = *reinterpret_cast<const bf16x8*>(bc + (2 * ct + 1) * 1024 + lane * 16);
      o[ct] = __builtin_amdgcn_mfma_f32_32x32x16_bf16(vf0, P0.v, o[ct], 0, 0, 0);
      o[ct] = __builtin_amdgcn_mfma_f32_32x32x16_bf16(vf1, P1.v, o[ct], 0, 0, 0);
    }
    __builtin_amdgcn_s_setprio(0);
    RBAR();                              // buf[pp] free for next overwrite

    kf0 = kn0; kf1 = kn1;
    pp ^= 1;
  }
  VMW("0");

  // ---- merge the two m-halves per qh (V bufs dead; Ob aliases them) ----
  L += __shfl_xor(L, 32);
  if (lane < 32) { sML[mh][qh][0][lane] = M; sML[mh][qh][1][lane] = L; }
  __syncthreads();
  float (*Ob)[256][33] = reinterpret_cast<float (*)[256][33]>(sbuf);
  float Ma = sML[0][qh][0][ln], La = sML[0][qh][1][ln];
  float Mb = sML[1][qh][0][ln], Lb = sML[1][qh][1][ln];
  float Ms = fmaxf(Ma, Mb);
  float a0 = EXP2(Ma - Ms), a1 = EXP2(Mb - Ms);
  float inv = 1.f / (La * a0 + Lb * a1);
  float a = mh ? a1 : a0;
  if (mh) {
#pragma unroll
    for (int ct = 0; ct < 8; ++ct)
#pragma unroll
      for (int r = 0; r < 16; ++r) {
        int c = ct * 32 + (r & 3) + 8 * (r >> 2) + 4 * h;
        Ob[qh][c][ln] = o[ct][r] * a;
      }
  }
  __syncthreads();
  if (!mh) {
#pragma unroll
    for (int ct = 0; ct < 8; ++ct)
#pragma unroll
      for (int r = 0; r < 16; ++r) {
        int c = ct * 32 + (r & 3) + 8 * (r >> 2) + 4 * h;
        size_t idx = ((size_t)b * C_ + c) * N_ + n0 + ln;
        out[idx] = (o[ct][r] * a + Ob[qh][c][ln]) * inv + x[idx];
      }
  }
}

extern "C" void kernel_launch(void* const* d_in, const int* in_sizes, int n_in,
                              void* d_out, int out_size, void* d_ws, size_t ws_size,
                              hipStream_t stream) {
  const float* x  = (const float*)d_in[0];
  const float* wq = (const float*)d_in[1];
  const float* bq = (const float*)d_in[2];
  const float* wk = (const float*)d_in[3];
  const float* bk = (const float*)d_in[4];
  const float* wv = (const float*)d_in[5];
  const float* bv = (const float*)d_in[6];
  float* out = (float*)d_out;

  bf16* xT = (bf16*)d_ws;
  bf16* Qt = xT + (size_t)B_ * N_ * C_;
  bf16* Kt = Qt + (size_t)B_ * N_ * C8_;
  bf16* Vt = Kt + (size_t)B_ * N_ * C8_;
  bf16* Wb = Vt + (size_t)B_ * N_ * C_;

  k_convw<<<dim3(80), dim3(256), 0, stream>>>(wq, wk, wv, Wb);
  k_transpose<<<dim3(2048), dim3(256), 0, stream>>>(x, xT);
  k_proj_all<<<dim3(256), dim3(256), 0, stream>>>(xT, Wb, bq, bk, bv, Qt, Kt, Vt);
  k_attn<<<dim3(512), dim3(256), 0, stream>>>(Qt, Kt, Vt, x, out);
}